// Round 1
// baseline (783.846 us; speedup 1.0000x reference)
//
#include <hip/hip_runtime.h>
#include <cstddef>
#include <cstdint>

// ---------------------------------------------------------------------------
// MultiheadSelfAttention: x->QKV proj -> per-head RMSNorm(q,k) -> full attn
// -> out proj.  B=4, T=2048, D=2048, H=16, Hd=128.  All compute in bf16 MFMA
// with fp32 accumulation; softmax/rmsnorm in fp32.
// ---------------------------------------------------------------------------

typedef __attribute__((ext_vector_type(8))) short sh8;     // 8 bf16 (4 VGPR)
typedef __attribute__((ext_vector_type(4))) float fx4;     // MFMA acc
typedef __attribute__((ext_vector_type(4))) unsigned short us4;
typedef __attribute__((ext_vector_type(4))) float f4;

#define DEVI __device__ __forceinline__

DEVI unsigned short f2bf(float f) {  // round-to-nearest-even f32 -> bf16
  union { float f; unsigned u; } v; v.f = f;
  return (unsigned short)((v.u + 0x7FFFu + ((v.u >> 16) & 1u)) >> 16);
}
DEVI float bf2f(unsigned short h) {
  union { unsigned u; float f; } v; v.u = ((unsigned)h) << 16;
  return v.f;
}
DEVI void gload16(const void* g, void* l) {  // async global->LDS, 16B/lane
  __builtin_amdgcn_global_load_lds((const __attribute__((address_space(1))) void*)g,
                                   (__attribute__((address_space(3))) void*)l, 16, 0, 0);
}

// ------------------------------- converts ----------------------------------
__global__ __launch_bounds__(256) void k_cvt(const float* __restrict__ in,
                                             unsigned short* __restrict__ out, int n4) {
  int i = blockIdx.x * 256 + threadIdx.x;
  if (i >= n4) return;
  f4 v = ((const f4*)in)[i];
  us4 o;
  o[0] = f2bf(v[0]); o[1] = f2bf(v[1]); o[2] = f2bf(v[2]); o[3] = f2bf(v[3]);
  ((us4*)out)[i] = o;
}

__global__ __launch_bounds__(256) void k_cvt_w(const float* __restrict__ w0, const float* __restrict__ w1,
                                               const float* __restrict__ w2, const float* __restrict__ w3,
                                               unsigned short* __restrict__ o0, unsigned short* __restrict__ o1,
                                               unsigned short* __restrict__ o2, unsigned short* __restrict__ o3) {
  const int which = blockIdx.y;
  const float* in = which == 0 ? w0 : which == 1 ? w1 : which == 2 ? w2 : w3;
  unsigned short* out = which == 0 ? o0 : which == 1 ? o1 : which == 2 ? o2 : o3;
  int i = blockIdx.x * 256 + threadIdx.x;
  f4 v = ((const f4*)in)[i];
  us4 o;
  o[0] = f2bf(v[0]); o[1] = f2bf(v[1]); o[2] = f2bf(v[2]); o[3] = f2bf(v[3]);
  ((us4*)out)[i] = o;
}

// ------------------------------ GEMM core ----------------------------------
// C[m,n] = sum_k A[m,k]*B[n,k]  (torch Linear: B = W [N,K] row-major)
// m97 structure: 128x128 tile, BK=32, 4 waves in 2x2, global_load_lds w=16.
__device__ inline void gemm_mainloop(const unsigned short* __restrict__ A,
                                     const unsigned short* __restrict__ Bw,
                                     unsigned short* As, unsigned short* Bs,
                                     int m0, int n0, fx4 (&acc)[4][4]) {
  constexpr int K = 2048;
  const int tid = threadIdx.x;
  const int lane = tid & 63, ln = lane & 15, hi = lane >> 4;
  const int wid = tid >> 6, wr = wid >> 1, wc = wid & 1;
  // staging: chunk c covers LDS bytes [c*16, c*16+16); row = c>>2, k-off = (c&3)*8
  const int c0 = tid, c1 = tid + 256;
  const int r0 = c0 >> 2, o0 = (c0 & 3) * 8;
  const int r1 = c1 >> 2, o1 = (c1 & 3) * 8;
  const unsigned short* Ab = A + (size_t)m0 * K;
  const unsigned short* Bb = Bw + (size_t)n0 * K;

  for (int k0 = 0; k0 < K; k0 += 32) {
    __syncthreads();  // previous tile's LDS reads done
    gload16(Ab + (size_t)r0 * K + k0 + o0, (char*)As + c0 * 16);
    gload16(Ab + (size_t)r1 * K + k0 + o1, (char*)As + c1 * 16);
    gload16(Bb + (size_t)r0 * K + k0 + o0, (char*)Bs + c0 * 16);
    gload16(Bb + (size_t)r1 * K + k0 + o1, (char*)Bs + c1 * 16);
    __syncthreads();  // compiler drains vmcnt before barrier
    sh8 af[4], bf[4];
#pragma unroll
    for (int mi = 0; mi < 4; ++mi)
      af[mi] = *(const sh8*)&As[(wr * 64 + mi * 16 + ln) * 32 + hi * 8];
#pragma unroll
    for (int ni = 0; ni < 4; ++ni)
      bf[ni] = *(const sh8*)&Bs[(wc * 64 + ni * 16 + ln) * 32 + hi * 8];
#pragma unroll
    for (int mi = 0; mi < 4; ++mi)
#pragma unroll
      for (int ni = 0; ni < 4; ++ni)
        acc[mi][ni] = __builtin_amdgcn_mfma_f32_16x16x32_bf16(af[mi], bf[ni], acc[mi][ni], 0, 0, 0);
  }
}

// QKV projection: z in {0,1,2} picks W/bias/out. Epilogue writes bf16 into
// attention layout [B=4][H=16][T=2048][Hd=128].
__global__ __launch_bounds__(256) void k_gemm_qkv(
    const unsigned short* __restrict__ A,
    const unsigned short* __restrict__ W0, const unsigned short* __restrict__ W1,
    const unsigned short* __restrict__ W2,
    const float* __restrict__ b0, const float* __restrict__ b1, const float* __restrict__ b2,
    unsigned short* __restrict__ O0, unsigned short* __restrict__ O1, unsigned short* __restrict__ O2) {
  __shared__ __align__(16) unsigned short As[128 * 32];
  __shared__ __align__(16) unsigned short Bs[128 * 32];
  const int z = blockIdx.z;
  const unsigned short* Bw = z == 0 ? W0 : z == 1 ? W1 : W2;
  const float* bias = z == 0 ? b0 : z == 1 ? b1 : b2;
  unsigned short* Cout = z == 0 ? O0 : z == 1 ? O1 : O2;
  const int m0 = blockIdx.y * 128, n0 = blockIdx.x * 128;
  fx4 acc[4][4] = {};
  gemm_mainloop(A, Bw, As, Bs, m0, n0, acc);

  const int lane = threadIdx.x & 63, ln = lane & 15, hi = lane >> 4;
  const int wid = threadIdx.x >> 6, wr = wid >> 1, wc = wid & 1;
#pragma unroll
  for (int mi = 0; mi < 4; ++mi) {
#pragma unroll
    for (int ni = 0; ni < 4; ++ni) {
      const int col = n0 + wc * 64 + ni * 16 + ln;
      const float bv = bias[col];
      const int h = col >> 7, d = col & 127;
#pragma unroll
      for (int j = 0; j < 4; ++j) {
        const int row = m0 + wr * 64 + mi * 16 + hi * 4 + j;
        const int b = row >> 11, t = row & 2047;
        Cout[((((size_t)b * 16 + h) * 2048) + t) * 128 + d] = f2bf(acc[mi][ni][j] + bv);
      }
    }
  }
}

// Output projection: fp32 row-major out + bias.
__global__ __launch_bounds__(256) void k_gemm_out(const unsigned short* __restrict__ A,
                                                  const unsigned short* __restrict__ Bw,
                                                  const float* __restrict__ bias,
                                                  float* __restrict__ C) {
  constexpr int N = 2048;
  __shared__ __align__(16) unsigned short As[128 * 32];
  __shared__ __align__(16) unsigned short Bs[128 * 32];
  const int m0 = blockIdx.y * 128, n0 = blockIdx.x * 128;
  fx4 acc[4][4] = {};
  gemm_mainloop(A, Bw, As, Bs, m0, n0, acc);

  const int lane = threadIdx.x & 63, ln = lane & 15, hi = lane >> 4;
  const int wid = threadIdx.x >> 6, wr = wid >> 1, wc = wid & 1;
#pragma unroll
  for (int mi = 0; mi < 4; ++mi) {
#pragma unroll
    for (int ni = 0; ni < 4; ++ni) {
      const int col = n0 + wc * 64 + ni * 16 + ln;
      const float bv = bias[col];
#pragma unroll
      for (int j = 0; j < 4; ++j) {
        const int row = m0 + wr * 64 + mi * 16 + hi * 4 + j;
        C[(size_t)row * N + col] = acc[mi][ni][j] + bv;
      }
    }
  }
}

// --------------------------- RMSNorm (in-place) ----------------------------
// One wave per 128-elem head row; Q also gets the 1/sqrt(Hd) softmax scale.
__global__ __launch_bounds__(256) void k_rms2(unsigned short* __restrict__ Qb,
                                              unsigned short* __restrict__ Kb,
                                              const float* __restrict__ qw,
                                              const float* __restrict__ kw) {
  const int which = blockIdx.y;
  unsigned short* X = which ? Kb : Qb;
  const float* w = which ? kw : qw;
  const float scale = which ? 1.0f : 0.08838834764831845f;  // 1/sqrt(128)
  const int row = blockIdx.x * 4 + (threadIdx.x >> 6);
  const int lane = threadIdx.x & 63;
  unsigned* p = (unsigned*)(X + (size_t)row * 128) + lane;  // 2 bf16/lane
  const unsigned u = *p;
  float a = bf2f((unsigned short)(u & 0xffffu));
  float b = bf2f((unsigned short)(u >> 16));
  float ss = a * a + b * b;
#pragma unroll
  for (int m = 1; m < 64; m <<= 1) ss += __shfl_xor(ss, m);
  const float r = rsqrtf(ss * (1.0f / 128.0f) + 1.1920928955078125e-07f) * scale;
  const float w0 = w[lane * 2], w1 = w[lane * 2 + 1];
  *p = (unsigned)f2bf(a * r * w0) | ((unsigned)f2bf(b * r * w1) << 16);
}

// --------------------------- V transpose -----------------------------------
// V [B,H,T,Hd] bf16 -> Vt [B,H,Hd,T] bf16 (64x64 LDS tiles).
__global__ __launch_bounds__(256) void k_transpose(const unsigned short* __restrict__ V,
                                                   unsigned short* __restrict__ Vt) {
  __shared__ unsigned short tile[64][65];
  const int bh = blockIdx.z;
  const int d0 = blockIdx.y * 64, t0 = blockIdx.x * 64;
  const int cg = threadIdx.x & 15, rr = threadIdx.x >> 4;
  const unsigned short* Vb = V + ((size_t)bh * 2048 + t0) * 128 + d0;
#pragma unroll
  for (int i = 0; i < 4; ++i) {
    const int r = rr + i * 16;
    us4 v = *(const us4*)(Vb + (size_t)r * 128 + cg * 4);
    tile[r][cg * 4 + 0] = v[0];
    tile[r][cg * 4 + 1] = v[1];
    tile[r][cg * 4 + 2] = v[2];
    tile[r][cg * 4 + 3] = v[3];
  }
  __syncthreads();
  unsigned short* Ob = Vt + ((size_t)bh * 128 + d0) * 2048 + t0;
#pragma unroll
  for (int i = 0; i < 4; ++i) {
    const int d = rr + i * 16;
    us4 v;
    v[0] = tile[cg * 4 + 0][d];
    v[1] = tile[cg * 4 + 1][d];
    v[2] = tile[cg * 4 + 2][d];
    v[3] = tile[cg * 4 + 3][d];
    *(us4*)(Ob + (size_t)d * 2048 + cg * 4) = v;
  }
}

// --------------------------- Flash attention -------------------------------
// 4 waves x 32 q-rows (BQ=128), KV tile = 64.  Online softmax, fully
// wave-parallel.  Writes attn-out bf16 in [M=8192][D=2048] row-major.
__global__ __launch_bounds__(256) void k_attn(const unsigned short* __restrict__ Q,
                                              const unsigned short* __restrict__ Kt,
                                              const unsigned short* __restrict__ Vt,
                                              unsigned short* __restrict__ Aout) {
  constexpr int T = 2048, Hd = 128;
  __shared__ __align__(16) unsigned short Ks[64 * 128];
  __shared__ __align__(16) unsigned short Vs[128 * 64];
  __shared__ __align__(16) unsigned short Ps[4 * 32 * 64];  // wave-private P
  const int tid = threadIdx.x;
  const int w = tid >> 6, lane = tid & 63;
  const int ln = lane & 15, hi = lane >> 4;
  const int bh = blockIdx.y;
  const int q0 = blockIdx.x * 128 + w * 32;

  // Q fragments in registers (A-operand: row=ln, k = ks*32 + hi*8)
  sh8 qf[2][4];
  const unsigned short* Qb = Q + ((size_t)bh * T + q0) * Hd;
#pragma unroll
  for (int mi = 0; mi < 2; ++mi)
#pragma unroll
    for (int ks = 0; ks < 4; ++ks)
      qf[mi][ks] = *(const sh8*)(Qb + (size_t)(mi * 16 + ln) * Hd + ks * 32 + hi * 8);

  fx4 o[2][8] = {};
  float mrun[2][4], lrun[2][4];
#pragma unroll
  for (int mi = 0; mi < 2; ++mi)
#pragma unroll
    for (int j = 0; j < 4; ++j) { mrun[mi][j] = -1e30f; lrun[mi][j] = 0.0f; }

  const unsigned short* Kgb = Kt + (size_t)bh * T * Hd;
  const unsigned short* Vgb = Vt + (size_t)bh * Hd * T;
  unsigned short* Pw = Ps + w * 2048;

  for (int t0 = 0; t0 < T; t0 += 64) {
    __syncthreads();
    // stage K tile [64][128]
#pragma unroll
    for (int i = 0; i < 4; ++i) {
      const int c = i * 256 + tid;
      gload16(Kgb + (size_t)(t0 + (c >> 4)) * Hd + (c & 15) * 8, (char*)Ks + c * 16);
    }
    // stage Vt tile [128][64]
#pragma unroll
    for (int i = 0; i < 4; ++i) {
      const int c = i * 256 + tid;
      gload16(Vgb + (size_t)(c >> 3) * T + t0 + (c & 7) * 8, (char*)Vs + c * 16);
    }
    __syncthreads();

    // S = Q K^T  (scale pre-folded into Q)
    fx4 s[2][4] = {};
#pragma unroll
    for (int ni = 0; ni < 4; ++ni) {
      sh8 kf[4];
#pragma unroll
      for (int ks = 0; ks < 4; ++ks)
        kf[ks] = *(const sh8*)&Ks[(ni * 16 + ln) * 128 + ks * 32 + hi * 8];
#pragma unroll
      for (int mi = 0; mi < 2; ++mi)
#pragma unroll
        for (int ks = 0; ks < 4; ++ks)
          s[mi][ni] = __builtin_amdgcn_mfma_f32_16x16x32_bf16(qf[mi][ks], kf[ks], s[mi][ni], 0, 0, 0);
    }

    // online softmax (rows live on 16-lane groups; shfl-xor row reduce)
#pragma unroll
    for (int mi = 0; mi < 2; ++mi) {
      float tm[4];
#pragma unroll
      for (int j = 0; j < 4; ++j)
        tm[j] = fmaxf(fmaxf(s[mi][0][j], s[mi][1][j]), fmaxf(s[mi][2][j], s[mi][3][j]));
#pragma unroll
      for (int m = 1; m < 16; m <<= 1)
#pragma unroll
        for (int j = 0; j < 4; ++j) tm[j] = fmaxf(tm[j], __shfl_xor(tm[j], m));
      float al[4], rs[4];
#pragma unroll
      for (int j = 0; j < 4; ++j) {
        const float mn = fmaxf(mrun[mi][j], tm[j]);
        al[j] = __expf(mrun[mi][j] - mn);
        mrun[mi][j] = mn;
        rs[j] = 0.0f;
      }
#pragma unroll
      for (int ni = 0; ni < 4; ++ni)
#pragma unroll
        for (int j = 0; j < 4; ++j) {
          const float p = __expf(s[mi][ni][j] - mrun[mi][j]);
          rs[j] += p;
          Pw[(mi * 16 + hi * 4 + j) * 64 + ni * 16 + ln] = f2bf(p);
        }
#pragma unroll
      for (int m = 1; m < 16; m <<= 1)
#pragma unroll
        for (int j = 0; j < 4; ++j) rs[j] += __shfl_xor(rs[j], m);
      fx4 av;
#pragma unroll
      for (int j = 0; j < 4; ++j) {
        lrun[mi][j] = lrun[mi][j] * al[j] + rs[j];
        av[j] = al[j];
      }
#pragma unroll
      for (int di = 0; di < 8; ++di) o[mi][di] *= av;
    }

    // O += P V   (A = P from LDS, B = Vt rows)
#pragma unroll
    for (int ks = 0; ks < 2; ++ks) {
      sh8 pf[2];
#pragma unroll
      for (int mi = 0; mi < 2; ++mi)
        pf[mi] = *(const sh8*)&Pw[(mi * 16 + ln) * 64 + ks * 32 + hi * 8];
#pragma unroll
      for (int di = 0; di < 8; ++di) {
        const sh8 vf = *(const sh8*)&Vs[(di * 16 + ln) * 64 + ks * 32 + hi * 8];
#pragma unroll
        for (int mi = 0; mi < 2; ++mi)
          o[mi][di] = __builtin_amdgcn_mfma_f32_16x16x32_bf16(pf[mi], vf, o[mi][di], 0, 0, 0);
      }
    }
  }

  // epilogue: O /= l, write bf16 attn-out in [M][2048] layout
  const int b = bh >> 4, h = bh & 15;
  unsigned short* Ob = Aout + ((size_t)b * T + q0) * 2048 + h * 128;
#pragma unroll
  for (int mi = 0; mi < 2; ++mi) {
    fx4 rv;
#pragma unroll
    for (int j = 0; j < 4; ++j) rv[j] = 1.0f / lrun[mi][j];
#pragma unroll
    for (int di = 0; di < 8; ++di) {
      fx4 val = o[mi][di] * rv;
#pragma unroll
      for (int j = 0; j < 4; ++j)
        Ob[(size_t)(mi * 16 + hi * 4 + j) * 2048 + di * 16 + ln] = f2bf(val[j]);
    }
  }
}

// ---------------------------------------------------------------------------
extern "C" void kernel_launch(void* const* d_in, const int* in_sizes, int n_in,
                              void* d_out, int out_size, void* d_ws, size_t ws_size,
                              hipStream_t stream) {
  const float* x   = (const float*)d_in[0];
  const float* Wq  = (const float*)d_in[1];
  const float* bq  = (const float*)d_in[2];
  const float* Wk  = (const float*)d_in[3];
  const float* bk  = (const float*)d_in[4];
  const float* Wv  = (const float*)d_in[5];
  const float* bv  = (const float*)d_in[6];
  const float* qnw = (const float*)d_in[7];
  const float* knw = (const float*)d_in[8];
  const float* Wo  = (const float*)d_in[9];
  const float* bo  = (const float*)d_in[10];
  float* out = (float*)d_out;

  // workspace layout (192 MB total)
  const size_t SZ_X = 33554432;  // 8192*2048 bf16
  const size_t SZ_W = 8388608;   // 2048*2048 bf16
  char* ws = (char*)d_ws;
  unsigned short* xb  = (unsigned short*)(ws);
  unsigned short* Wqb = (unsigned short*)(ws + SZ_X);
  unsigned short* Wkb = (unsigned short*)(ws + SZ_X + SZ_W);
  unsigned short* Wvb = (unsigned short*)(ws + SZ_X + 2 * SZ_W);
  unsigned short* Wob = (unsigned short*)(ws + SZ_X + 3 * SZ_W);
  unsigned short* Qb  = (unsigned short*)(ws + SZ_X + 4 * SZ_W);
  unsigned short* Kb  = (unsigned short*)(ws + 2 * SZ_X + 4 * SZ_W);
  unsigned short* Vb  = (unsigned short*)(ws + 3 * SZ_X + 4 * SZ_W);
  unsigned short* Vtb = (unsigned short*)(ws + 4 * SZ_X + 4 * SZ_W);
  unsigned short* AOb = Vb;  // V layout dead after transpose; reuse for attn-out

  // 1) convert inputs to bf16
  k_cvt<<<16384, 256, 0, stream>>>(x, xb, 4194304);
  k_cvt_w<<<dim3(4096, 4), 256, 0, stream>>>(Wq, Wk, Wv, Wo, Wqb, Wkb, Wvb, Wob);
  // 2) fused QKV projection -> [B,H,T,Hd] bf16
  k_gemm_qkv<<<dim3(16, 64, 3), 256, 0, stream>>>(xb, Wqb, Wkb, Wvb, bq, bk, bv, Qb, Kb, Vb);
  // 3) per-head RMSNorm on Q (with softmax scale) and K, in place
  k_rms2<<<dim3(32768, 2), 256, 0, stream>>>(Qb, Kb, qnw, knw);
  // 4) V -> V^T for contiguous PV B-operand
  k_transpose<<<dim3(32, 2, 64), 256, 0, stream>>>(Vb, Vtb);
  // 5) flash attention -> attn-out bf16 [8192][2048]
  k_attn<<<dim3(16, 64), 256, 0, stream>>>(Qb, Kb, Vtb, AOb);
  // 6) output projection -> fp32 d_out
  k_gemm_out<<<dim3(16, 64), 256, 0, stream>>>(AOb, Wob, bo, out);
}